// Round 4
// baseline (167.390 us; speedup 1.0000x reference)
//
#include <hip/hip_runtime.h>
#include <math.h>

#define DIM 96
#define NE 4
#define HH 128
#define WW 128
#define BB 16
#define KP 24   // padded k-stride (u16) for hs/pwT rows: 48 B, 16B-aligned

typedef __attribute__((ext_vector_type(8))) __bf16 bf16x8;
typedef __attribute__((ext_vector_type(4))) float floatx4;

__device__ __forceinline__ unsigned short f2bf(float f) {
    unsigned u = __builtin_bit_cast(unsigned, f);
    unsigned r = u + 0x7FFFu + ((u >> 16) & 1u);   // RNE
    return (unsigned short)(r >> 16);
}
__device__ __forceinline__ unsigned pack2(float a, float b) {
    return (unsigned)f2bf(a) | ((unsigned)f2bf(b) << 16);
}

// exact-erf GELU via Abramowitz-Stegun 7.1.26 (|eps| <= 1.5e-7), branchless
__device__ __forceinline__ float gelu_erf(float h) {
    const float x = h * 0.70710678118654752f;
    const float a = fabsf(x);
    const float t = __builtin_amdgcn_rcpf(__builtin_fmaf(0.3275911f, a, 1.0f));
    float p = __builtin_fmaf(1.061405429f, t, -1.453152027f);
    p = __builtin_fmaf(p, t, 1.421413741f);
    p = __builtin_fmaf(p, t, -0.284496736f);
    p = __builtin_fmaf(p, t, 0.254829592f);
    p *= t;
    const float e = __expf(-x * x);
    float erfv = __builtin_fmaf(-p, e, 1.0f);
    erfv = copysignf(erfv, x);
    return 0.5f * h * (1.0f + erfv);
}

// ---------------- Kernel A: per-(b,c) mean pool ----------------
__global__ __launch_bounds__(256) void pool_kernel(const float* __restrict__ x,
                                                   float* __restrict__ pooled) {
    const int bc = blockIdx.x;
    const float4* p = (const float4*)(x + (size_t)bc * (HH * WW));
    const int t = threadIdx.x;
    float s = 0.f;
#pragma unroll
    for (int k = 0; k < (HH * WW / 4) / 256; ++k) {
        float4 v = p[t + k * 256];
        s += v.x + v.y + v.z + v.w;
    }
#pragma unroll
    for (int off = 32; off; off >>= 1) s += __shfl_down(s, off, 64);
    __shared__ float ls[4];
    if ((t & 63) == 0) ls[t >> 6] = s;
    __syncthreads();
    if (t == 0) pooled[bc] = (ls[0] + ls[1] + ls[2] + ls[3]) * (1.0f / (HH * WW));
}

// ---------------- Kernel B: router ----------------
__global__ void router_kernel(const float* __restrict__ pooled,
                              const float* __restrict__ rw,
                              const float* __restrict__ rb,
                              float* __restrict__ gate, int* __restrict__ sel) {
    const int b = threadIdx.x;
    if (b >= BB) return;
    float logits[NE];
#pragma unroll
    for (int e = 0; e < NE; ++e) {
        float s = rb[e];
        for (int c = 0; c < DIM; ++c) s += pooled[b * DIM + c] * rw[e * DIM + c];
        logits[e] = s;
    }
    float m = logits[0];
    int mi = 0;
#pragma unroll
    for (int e = 1; e < NE; ++e)
        if (logits[e] > m) { m = logits[e]; mi = e; }
    float denom = 0.f;
#pragma unroll
    for (int e = 0; e < NE; ++e) denom += expf(logits[e] - m);
    float w = 1.0f / denom;
    gate[b] = w / (w + 1e-8f);
    sel[b] = mi;
}

// ---------------- Kernel C: fused expert, 1 row per block ----------------
// 256 threads = 4 waves. Thread owns 4 consecutive px x 2 ch per 16-ch sub:
// float4 row loads (2.25 loads/px), row-edge masks folded into staged taps,
// A&S-erf GELU. hs writes/reads XOR-swizzled to kill bank conflicts.
__global__ __launch_bounds__(256, 5) void moe_main(
    const float* __restrict__ x, const float* __restrict__ dw_w,
    const float* __restrict__ dw_b, const float* __restrict__ pw_w,
    const float* __restrict__ pw_b, const float* __restrict__ gate,
    const int* __restrict__ sel, float* __restrict__ out) {
    __shared__ __align__(16) unsigned char hsb[2][WW * KP * 2];  // 12 KB [sub]
    __shared__ unsigned short pwT[2][DIM][KP];                   // 9 KB
    __shared__ float dwc[DIM][12];                               // 4.6 KB

    const int t = threadIdx.x;
    // XCD-chunked swizzle: each XCD gets 2 images' worth of consecutive rows
    const unsigned o = blockIdx.x;
    const unsigned wid = (o & 7) * 256 + (o >> 3);
    const int b = wid >> 7;        // 0..15
    const int r = wid & 127;       // 0..127
    const int e = sel[b];
    const float g = gate[b];

    const int lane = t & 63, w = t >> 6;
    const int wm = w & 1, wn = w >> 1;
    const int ln = lane & 15, kg = lane >> 4;
    const int cobase = wm * 48, pxbase = wn * 64;

    const int g32 = t & 31;        // px group (4 px each)
    const int p4 = g32 * 4;
    const int cg = t >> 5;         // 0..7 channel group (2 ch each)
    const unsigned swz = (unsigned)((g32 & 7) << 4);
    const int lidx = (p4 == 0) ? 0 : p4 - 1;
    const int ridx = (p4 == 124) ? 127 : p4 + 4;
    const float lmask = (p4 == 0) ? 0.f : 1.f;
    const float rmask = (p4 == 124) ? 0.f : 1.f;

    const float m0 = (r > 0) ? 1.f : 0.f;
    const float m2 = (r < HH - 1) ? 1.f : 0.f;
    const int rr0 = (r > 0) ? r - 1 : 0;
    const int rr2 = (r < HH - 1) ? r + 1 : HH - 1;

    // stage depthwise taps + bias, row-edge masks folded in
    for (int j = t; j < DIM * 12; j += 256) {
        const int c = j / 12, q = j - c * 12;
        float v = 0.f;
        if (q < 9) {
            v = dw_w[((size_t)e * DIM + c) * 9 + q];
            if (q < 3) v *= m0;
            if (q >= 6) v *= m2;
        } else if (q == 9) v = dw_b[e * DIM + c];
        dwc[c][q] = v;
    }
    __syncthreads();

    floatx4 acc[3][4];
#pragma unroll
    for (int i = 0; i < 3; ++i)
#pragma unroll
        for (int j = 0; j < 4; ++j) acc[i][j] = (floatx4){0.f, 0.f, 0.f, 0.f};

    for (int pair = 0; pair < 3; ++pair) {
#pragma unroll
        for (int sub = 0; sub < 2; ++sub) {
            const int cb = pair * 32 + sub * 16;
            float hq[2][4];
#pragma unroll
            for (int u = 0; u < 2; ++u) {
                const int c = cb + cg * 2 + u;
                const float* pl = x + (size_t)(b * DIM + c) * (HH * WW);
                const float4 wA = *(const float4*)&dwc[c][0];   // q0..q3
                const float4 wB = *(const float4*)&dwc[c][4];   // q4..q7
                const float4 wC = *(const float4*)&dwc[c][8];   // q8, bias
                float h0 = wC.y, h1 = wC.y, h2 = wC.y, h3 = wC.y;
#pragma unroll
                for (int row = 0; row < 3; ++row) {
                    const int ri = (row == 0) ? rr0 : ((row == 1) ? r : rr2);
                    const float ta = (row == 0) ? wA.x : ((row == 1) ? wA.w : wB.z);
                    const float tb = (row == 0) ? wA.y : ((row == 1) ? wB.x : wB.w);
                    const float tc = (row == 0) ? wA.z : ((row == 1) ? wB.y : wC.x);
                    const float* pr = pl + ri * WW;
                    const float4 f4 = *(const float4*)(pr + p4);
                    const float vl = pr[lidx] * lmask;
                    const float vr = pr[ridx] * rmask;
                    h0 = __builtin_fmaf(ta, vl,   __builtin_fmaf(tb, f4.x, __builtin_fmaf(tc, f4.y, h0)));
                    h1 = __builtin_fmaf(ta, f4.x, __builtin_fmaf(tb, f4.y, __builtin_fmaf(tc, f4.z, h1)));
                    h2 = __builtin_fmaf(ta, f4.y, __builtin_fmaf(tb, f4.z, __builtin_fmaf(tc, f4.w, h2)));
                    h3 = __builtin_fmaf(ta, f4.z, __builtin_fmaf(tb, f4.w, __builtin_fmaf(tc, vr, h3)));
                }
                hq[u][0] = gelu_erf(h0);
                hq[u][1] = gelu_erf(h1);
                hq[u][2] = gelu_erf(h2);
                hq[u][3] = gelu_erf(h3);
            }
            // hs[sub][px][k]: write 4 dwords, XOR-swizzled
            const unsigned wb0 = (unsigned)(p4 * (KP * 2) + cg * 4);
#pragma unroll
            for (int j = 0; j < 4; ++j) {
                const unsigned off = (wb0 + (unsigned)j * (KP * 2)) ^ swz;
                *(unsigned*)(hsb[sub] + off) = pack2(hq[0][j], hq[1][j]);
            }
            if (sub == 0) {
                // stage pw^T for both k-halves of this pair
#pragma unroll
                for (int p = 0; p < 2; ++p)
#pragma unroll
                    for (int i2 = 0; i2 < 3; ++i2) {
                        const int u2 = i2 * 256 + t;     // 0..767
                        const int co = u2 >> 3, kk = (u2 & 7) * 2;
                        const float2 v = *(const float2*)(pw_w +
                            ((size_t)e * DIM + co) * DIM + pair * 32 + p * 16 + kk);
                        *(unsigned*)&pwT[p][co][kk] = pack2(v.x, v.y);
                    }
            }
        }
        __syncthreads();

        // MFMA: K=32 over the two sub-buffers
        const int bufi = kg >> 1, klo = (kg & 1) * 8;
        bf16x8 af[3], bfr[4];
#pragma unroll
        for (int mf = 0; mf < 3; ++mf)
            af[mf] = *(const bf16x8*)&pwT[bufi][cobase + mf * 16 + ln][klo];
#pragma unroll
        for (int nf = 0; nf < 4; ++nf) {
            const int pxv = pxbase + nf * 16 + ln;
            const unsigned boff = (unsigned)((pxv * (KP * 2) + (kg & 1) * 16) ^
                                             (((pxv >> 2) & 7) << 4));
            bfr[nf] = *(const bf16x8*)(hsb[bufi] + boff);
        }
#pragma unroll
        for (int mf = 0; mf < 3; ++mf)
#pragma unroll
            for (int nf = 0; nf < 4; ++nf)
                acc[mf][nf] = __builtin_amdgcn_mfma_f32_16x16x32_bf16(
                    af[mf], bfr[nf], acc[mf][nf], 0, 0, 0);
        __syncthreads();
    }

    // epilogue: bias + gate, coalesced 64B segments
#pragma unroll
    for (int mf = 0; mf < 3; ++mf) {
#pragma unroll
        for (int rr = 0; rr < 4; ++rr) {
            const int co = cobase + mf * 16 + kg * 4 + rr;
            const float bias = pw_b[e * DIM + co];
            float* orow = out + ((size_t)(b * DIM + co) * HH + r) * WW;
#pragma unroll
            for (int nf = 0; nf < 4; ++nf)
                orow[pxbase + nf * 16 + ln] = (acc[mf][nf][rr] + bias) * g;
        }
    }
}

extern "C" void kernel_launch(void* const* d_in, const int* in_sizes, int n_in,
                              void* d_out, int out_size, void* d_ws, size_t ws_size,
                              hipStream_t stream) {
    const float* x    = (const float*)d_in[0];
    const float* dw_w = (const float*)d_in[1];
    const float* dw_b = (const float*)d_in[2];
    const float* pw_w = (const float*)d_in[3];
    const float* pw_b = (const float*)d_in[4];
    const float* rw   = (const float*)d_in[5];
    const float* rb   = (const float*)d_in[6];
    float* out = (float*)d_out;

    float* pooled = (float*)d_ws;              // B*C floats
    float* gate = pooled + BB * DIM;           // B floats
    int* sel = (int*)(gate + BB);              // B ints

    pool_kernel<<<BB * DIM, 256, 0, stream>>>(x, pooled);
    router_kernel<<<1, 64, 0, stream>>>(pooled, rw, rb, gate, sel);
    moe_main<<<HH * BB, 256, 0, stream>>>(x, dw_w, dw_b, pw_w, pw_b, gate, sel, out);
}

// Round 5
// 97.884 us; speedup vs baseline: 1.7101x; 1.7101x over previous
//
#include <hip/hip_runtime.h>
#include <math.h>

#define DIM 96
#define NE 4
#define HH 128
#define WW 128
#define BB 16
#define KP 24   // padded k-stride (u16) for hs/pwT rows: 48 B, 16B-aligned

typedef __attribute__((ext_vector_type(8))) __bf16 bf16x8;
typedef __attribute__((ext_vector_type(4))) float floatx4;

__device__ __forceinline__ unsigned short f2bf(float f) {
    unsigned u = __builtin_bit_cast(unsigned, f);
    unsigned r = u + 0x7FFFu + ((u >> 16) & 1u);   // RNE
    return (unsigned short)(r >> 16);
}
__device__ __forceinline__ unsigned pack2(float a, float b) {
    return (unsigned)f2bf(a) | ((unsigned)f2bf(b) << 16);
}

// exact-erf GELU via Abramowitz-Stegun 7.1.26 (|eps| <= 1.5e-7), branchless
__device__ __forceinline__ float gelu_erf(float h) {
    const float x = h * 0.70710678118654752f;
    const float a = fabsf(x);
    const float t = __builtin_amdgcn_rcpf(__builtin_fmaf(0.3275911f, a, 1.0f));
    float p = __builtin_fmaf(1.061405429f, t, -1.453152027f);
    p = __builtin_fmaf(p, t, 1.421413741f);
    p = __builtin_fmaf(p, t, -0.284496736f);
    p = __builtin_fmaf(p, t, 0.254829592f);
    p *= t;
    const float e = __expf(-x * x);
    float erfv = __builtin_fmaf(-p, e, 1.0f);
    erfv = copysignf(erfv, x);
    return 0.5f * h * (1.0f + erfv);
}

// ---------------- Kernel A: per-(b,c) mean pool ----------------
__global__ __launch_bounds__(256) void pool_kernel(const float* __restrict__ x,
                                                   float* __restrict__ pooled) {
    const int bc = blockIdx.x;
    const float4* p = (const float4*)(x + (size_t)bc * (HH * WW));
    const int t = threadIdx.x;
    float s = 0.f;
#pragma unroll
    for (int k = 0; k < (HH * WW / 4) / 256; ++k) {
        float4 v = p[t + k * 256];
        s += v.x + v.y + v.z + v.w;
    }
#pragma unroll
    for (int off = 32; off; off >>= 1) s += __shfl_down(s, off, 64);
    __shared__ float ls[4];
    if ((t & 63) == 0) ls[t >> 6] = s;
    __syncthreads();
    if (t == 0) pooled[bc] = (ls[0] + ls[1] + ls[2] + ls[3]) * (1.0f / (HH * WW));
}

// ---------------- Kernel B: router ----------------
__global__ void router_kernel(const float* __restrict__ pooled,
                              const float* __restrict__ rw,
                              const float* __restrict__ rb,
                              float* __restrict__ gate, int* __restrict__ sel) {
    const int b = threadIdx.x;
    if (b >= BB) return;
    float logits[NE];
#pragma unroll
    for (int e = 0; e < NE; ++e) {
        float s = rb[e];
        for (int c = 0; c < DIM; ++c) s += pooled[b * DIM + c] * rw[e * DIM + c];
        logits[e] = s;
    }
    float m = logits[0];
    int mi = 0;
#pragma unroll
    for (int e = 1; e < NE; ++e)
        if (logits[e] > m) { m = logits[e]; mi = e; }
    float denom = 0.f;
#pragma unroll
    for (int e = 0; e < NE; ++e) denom += expf(logits[e] - m);
    float w = 1.0f / denom;
    gate[b] = w / (w + 1e-8f);
    sel[b] = mi;
}

// ---------------- Kernel C: fused expert, 1 row per block ----------------
// 256 threads = 4 waves. Thread owns 4 consecutive px x 2 ch per 16-ch sub:
// one float4 row load per (row,ch); halo via __shfl within 32-lane px groups;
// row-edge masks folded into staged taps; A&S-erf GELU; hs XOR-swizzled.
__global__ __launch_bounds__(256, 4) void moe_main(
    const float* __restrict__ x, const float* __restrict__ dw_w,
    const float* __restrict__ dw_b, const float* __restrict__ pw_w,
    const float* __restrict__ pw_b, const float* __restrict__ gate,
    const int* __restrict__ sel, float* __restrict__ out) {
    __shared__ __align__(16) unsigned char hsb[2][WW * KP * 2];  // 12 KB [sub]
    __shared__ unsigned short pwT[2][DIM][KP];                   // 9 KB
    __shared__ float dwc[DIM][12];                               // 4.6 KB

    const int t = threadIdx.x;
    const int r = blockIdx.x;      // 0..127
    const int b = blockIdx.y;      // 0..15
    const int e = sel[b];
    const float g = gate[b];

    const int lane = t & 63, w = t >> 6;
    const int wm = w & 1, wn = w >> 1;
    const int ln = lane & 15, kg = lane >> 4;
    const int cobase = wm * 48, pxbase = wn * 64;

    const int g32 = t & 31;        // px group (4 px each)
    const int p4 = g32 * 4;
    const int cg = t >> 5;         // 0..7 channel group (2 ch each)
    const unsigned swz = (unsigned)((g32 & 7) << 4);
    const float lmask = (p4 == 0) ? 0.f : 1.f;
    const float rmask = (p4 == 124) ? 0.f : 1.f;

    const float m0 = (r > 0) ? 1.f : 0.f;
    const float m2 = (r < HH - 1) ? 1.f : 0.f;
    const int rr0 = (r > 0) ? r - 1 : 0;
    const int rr2 = (r < HH - 1) ? r + 1 : HH - 1;

    // stage depthwise taps + bias, row-edge masks folded in
    for (int j = t; j < DIM * 12; j += 256) {
        const int c = j / 12, q = j - c * 12;
        float v = 0.f;
        if (q < 9) {
            v = dw_w[((size_t)e * DIM + c) * 9 + q];
            if (q < 3) v *= m0;
            if (q >= 6) v *= m2;
        } else if (q == 9) v = dw_b[e * DIM + c];
        dwc[c][q] = v;
    }
    __syncthreads();

    floatx4 acc[3][4];
#pragma unroll
    for (int i = 0; i < 3; ++i)
#pragma unroll
        for (int j = 0; j < 4; ++j) acc[i][j] = (floatx4){0.f, 0.f, 0.f, 0.f};

    for (int pair = 0; pair < 3; ++pair) {
#pragma unroll
        for (int sub = 0; sub < 2; ++sub) {
            const int cb = pair * 32 + sub * 16;
            float hq[2][4];
#pragma unroll
            for (int u = 0; u < 2; ++u) {
                const int c = cb + cg * 2 + u;
                const float* pl = x + (size_t)(b * DIM + c) * (HH * WW);
                const float4 wA = *(const float4*)&dwc[c][0];   // q0..q3
                const float4 wB = *(const float4*)&dwc[c][4];   // q4..q7
                const float4 wC = *(const float4*)&dwc[c][8];   // q8, bias
                float h0 = wC.y, h1 = wC.y, h2 = wC.y, h3 = wC.y;
#pragma unroll
                for (int row = 0; row < 3; ++row) {
                    const int ri = (row == 0) ? rr0 : ((row == 1) ? r : rr2);
                    const float ta = (row == 0) ? wA.x : ((row == 1) ? wA.w : wB.z);
                    const float tb = (row == 0) ? wA.y : ((row == 1) ? wB.x : wB.w);
                    const float tc = (row == 0) ? wA.z : ((row == 1) ? wB.y : wC.x);
                    const float4 f4 = *(const float4*)(pl + ri * WW + p4);
                    const float vl = __shfl_up(f4.w, 1, 32) * lmask;
                    const float vr = __shfl_down(f4.x, 1, 32) * rmask;
                    h0 = __builtin_fmaf(ta, vl,   __builtin_fmaf(tb, f4.x, __builtin_fmaf(tc, f4.y, h0)));
                    h1 = __builtin_fmaf(ta, f4.x, __builtin_fmaf(tb, f4.y, __builtin_fmaf(tc, f4.z, h1)));
                    h2 = __builtin_fmaf(ta, f4.y, __builtin_fmaf(tb, f4.z, __builtin_fmaf(tc, f4.w, h2)));
                    h3 = __builtin_fmaf(ta, f4.z, __builtin_fmaf(tb, f4.w, __builtin_fmaf(tc, vr, h3)));
                }
                hq[u][0] = gelu_erf(h0);
                hq[u][1] = gelu_erf(h1);
                hq[u][2] = gelu_erf(h2);
                hq[u][3] = gelu_erf(h3);
            }
            // hs[sub][px][k]: write 4 dwords, XOR-swizzled
            const unsigned wb0 = (unsigned)(p4 * (KP * 2) + cg * 4);
#pragma unroll
            for (int j = 0; j < 4; ++j) {
                const unsigned off = (wb0 + (unsigned)j * (KP * 2)) ^ swz;
                *(unsigned*)(hsb[sub] + off) = pack2(hq[0][j], hq[1][j]);
            }
            if (sub == 0) {
                // stage pw^T for both k-halves of this pair
#pragma unroll
                for (int p = 0; p < 2; ++p)
#pragma unroll
                    for (int i2 = 0; i2 < 3; ++i2) {
                        const int u2 = i2 * 256 + t;     // 0..767
                        const int co = u2 >> 3, kk = (u2 & 7) * 2;
                        const float2 v = *(const float2*)(pw_w +
                            ((size_t)e * DIM + co) * DIM + pair * 32 + p * 16 + kk);
                        *(unsigned*)&pwT[p][co][kk] = pack2(v.x, v.y);
                    }
            }
        }
        __syncthreads();

        // MFMA: K=32 over the two sub-buffers
        const int bufi = kg >> 1, klo = (kg & 1) * 8;
        bf16x8 af[3], bfr[4];
#pragma unroll
        for (int mf = 0; mf < 3; ++mf)
            af[mf] = *(const bf16x8*)&pwT[bufi][cobase + mf * 16 + ln][klo];
#pragma unroll
        for (int nf = 0; nf < 4; ++nf) {
            const int pxv = pxbase + nf * 16 + ln;
            const unsigned boff = (unsigned)((pxv * (KP * 2) + (kg & 1) * 16) ^
                                             (((pxv >> 2) & 7) << 4));
            bfr[nf] = *(const bf16x8*)(hsb[bufi] + boff);
        }
#pragma unroll
        for (int mf = 0; mf < 3; ++mf)
#pragma unroll
            for (int nf = 0; nf < 4; ++nf)
                acc[mf][nf] = __builtin_amdgcn_mfma_f32_16x16x32_bf16(
                    af[mf], bfr[nf], acc[mf][nf], 0, 0, 0);
        __syncthreads();
    }

    // epilogue: bias + gate, coalesced 64B segments
#pragma unroll
    for (int mf = 0; mf < 3; ++mf) {
#pragma unroll
        for (int rr = 0; rr < 4; ++rr) {
            const int co = cobase + mf * 16 + kg * 4 + rr;
            const float bias = pw_b[e * DIM + co];
            float* orow = out + ((size_t)(b * DIM + co) * HH + r) * WW;
#pragma unroll
            for (int nf = 0; nf < 4; ++nf)
                orow[pxbase + nf * 16 + ln] = (acc[mf][nf][rr] + bias) * g;
        }
    }
}

extern "C" void kernel_launch(void* const* d_in, const int* in_sizes, int n_in,
                              void* d_out, int out_size, void* d_ws, size_t ws_size,
                              hipStream_t stream) {
    const float* x    = (const float*)d_in[0];
    const float* dw_w = (const float*)d_in[1];
    const float* dw_b = (const float*)d_in[2];
    const float* pw_w = (const float*)d_in[3];
    const float* pw_b = (const float*)d_in[4];
    const float* rw   = (const float*)d_in[5];
    const float* rb   = (const float*)d_in[6];
    float* out = (float*)d_out;

    float* pooled = (float*)d_ws;              // B*C floats
    float* gate = pooled + BB * DIM;           // B floats
    int* sel = (int*)(gate + BB);              // B ints

    pool_kernel<<<BB * DIM, 256, 0, stream>>>(x, pooled);
    router_kernel<<<1, 64, 0, stream>>>(pooled, rw, rb, gate, sel);
    dim3 grid(HH, BB);
    moe_main<<<grid, 256, 0, stream>>>(x, dw_w, dw_b, pw_w, pw_b, gate, sel, out);
}

// Round 6
// 91.987 us; speedup vs baseline: 1.8197x; 1.0641x over previous
//
#include <hip/hip_runtime.h>
#include <math.h>

#define DIM 96
#define NE 4
#define HH 128
#define WW 128
#define BB 16
#define KP 24   // padded k-stride (u16) for hs/pwT rows: 48 B, 16B-aligned

typedef __attribute__((ext_vector_type(8))) __bf16 bf16x8;
typedef __attribute__((ext_vector_type(4))) float floatx4;

__device__ __forceinline__ unsigned short f2bf(float f) {
    unsigned u = __builtin_bit_cast(unsigned, f);
    unsigned r = u + 0x7FFFu + ((u >> 16) & 1u);   // RNE
    return (unsigned short)(r >> 16);
}
__device__ __forceinline__ unsigned pack2(float a, float b) {
    return (unsigned)f2bf(a) | ((unsigned)f2bf(b) << 16);
}

// exact-erf GELU via Abramowitz-Stegun 7.1.26 (|eps| <= 1.5e-7), branchless
__device__ __forceinline__ float gelu_erf(float h) {
    const float x = h * 0.70710678118654752f;
    const float a = fabsf(x);
    const float t = __builtin_amdgcn_rcpf(__builtin_fmaf(0.3275911f, a, 1.0f));
    float p = __builtin_fmaf(1.061405429f, t, -1.453152027f);
    p = __builtin_fmaf(p, t, 1.421413741f);
    p = __builtin_fmaf(p, t, -0.284496736f);
    p = __builtin_fmaf(p, t, 0.254829592f);
    p *= t;
    const float e = __expf(-x * x);
    float erfv = __builtin_fmaf(-p, e, 1.0f);
    erfv = copysignf(erfv, x);
    return 0.5f * h * (1.0f + erfv);
}

// ---------------- Kernel A: per-(b,c) mean pool ----------------
__global__ __launch_bounds__(256) void pool_kernel(const float* __restrict__ x,
                                                   float* __restrict__ pooled) {
    const int bc = blockIdx.x;
    const float4* p = (const float4*)(x + (size_t)bc * (HH * WW));
    const int t = threadIdx.x;
    float s = 0.f;
#pragma unroll
    for (int k = 0; k < (HH * WW / 4) / 256; ++k) {
        float4 v = p[t + k * 256];
        s += v.x + v.y + v.z + v.w;
    }
#pragma unroll
    for (int off = 32; off; off >>= 1) s += __shfl_down(s, off, 64);
    __shared__ float ls[4];
    if ((t & 63) == 0) ls[t >> 6] = s;
    __syncthreads();
    if (t == 0) pooled[bc] = (ls[0] + ls[1] + ls[2] + ls[3]) * (1.0f / (HH * WW));
}

// ---------------- Kernel B: router ----------------
__global__ void router_kernel(const float* __restrict__ pooled,
                              const float* __restrict__ rw,
                              const float* __restrict__ rb,
                              float* __restrict__ gate, int* __restrict__ sel) {
    const int b = threadIdx.x;
    if (b >= BB) return;
    float logits[NE];
#pragma unroll
    for (int e = 0; e < NE; ++e) {
        float s = rb[e];
        for (int c = 0; c < DIM; ++c) s += pooled[b * DIM + c] * rw[e * DIM + c];
        logits[e] = s;
    }
    float m = logits[0];
    int mi = 0;
#pragma unroll
    for (int e = 1; e < NE; ++e)
        if (logits[e] > m) { m = logits[e]; mi = e; }
    float denom = 0.f;
#pragma unroll
    for (int e = 0; e < NE; ++e) denom += expf(logits[e] - m);
    float w = 1.0f / denom;
    gate[b] = w / (w + 1e-8f);
    sel[b] = mi;
}

// issue 6 float4 loads (2 ch x 3 rows) for one 16-ch sub-chunk
__device__ __forceinline__ void issue_sub(const float* __restrict__ x, int b,
                                          int cbase, int cg, int rr0, int r,
                                          int rr2, int p4, float4 f[2][3]) {
#pragma unroll
    for (int u = 0; u < 2; ++u) {
        const float* pl = x + (size_t)(b * DIM + cbase + cg * 2 + u) * (HH * WW);
        f[u][0] = *(const float4*)(pl + rr0 * WW + p4);
        f[u][1] = *(const float4*)(pl + r   * WW + p4);
        f[u][2] = *(const float4*)(pl + rr2 * WW + p4);
    }
}

// depthwise taps + GELU from preloaded registers -> swizzled hs writes
__device__ __forceinline__ void compute_sub(const float4 f[2][3],
                                            const float (*dwc)[12], int cb,
                                            int cg, float lmask, float rmask,
                                            unsigned char* hsbuf, int p4,
                                            unsigned swz) {
    float hq[2][4];
#pragma unroll
    for (int u = 0; u < 2; ++u) {
        const int c = cb + cg * 2 + u;
        const float4 wA = *(const float4*)&dwc[c][0];   // q0..q3
        const float4 wB = *(const float4*)&dwc[c][4];   // q4..q7
        const float4 wC = *(const float4*)&dwc[c][8];   // q8, bias
        float h0 = wC.y, h1 = wC.y, h2 = wC.y, h3 = wC.y;
#pragma unroll
        for (int row = 0; row < 3; ++row) {
            const float ta = (row == 0) ? wA.x : ((row == 1) ? wA.w : wB.z);
            const float tb = (row == 0) ? wA.y : ((row == 1) ? wB.x : wB.w);
            const float tc = (row == 0) ? wA.z : ((row == 1) ? wB.y : wC.x);
            const float4 f4 = f[u][row];
            const float vl = __shfl_up(f4.w, 1, 32) * lmask;
            const float vr = __shfl_down(f4.x, 1, 32) * rmask;
            h0 = __builtin_fmaf(ta, vl,   __builtin_fmaf(tb, f4.x, __builtin_fmaf(tc, f4.y, h0)));
            h1 = __builtin_fmaf(ta, f4.x, __builtin_fmaf(tb, f4.y, __builtin_fmaf(tc, f4.z, h1)));
            h2 = __builtin_fmaf(ta, f4.y, __builtin_fmaf(tb, f4.z, __builtin_fmaf(tc, f4.w, h2)));
            h3 = __builtin_fmaf(ta, f4.z, __builtin_fmaf(tb, f4.w, __builtin_fmaf(tc, vr, h3)));
        }
        hq[u][0] = gelu_erf(h0);
        hq[u][1] = gelu_erf(h1);
        hq[u][2] = gelu_erf(h2);
        hq[u][3] = gelu_erf(h3);
    }
    const unsigned wb0 = (unsigned)(p4 * (KP * 2) + cg * 4);
#pragma unroll
    for (int j = 0; j < 4; ++j) {
        const unsigned off = (wb0 + (unsigned)j * (KP * 2)) ^ swz;
        *(unsigned*)(hsbuf + off) = pack2(hq[0][j], hq[1][j]);
    }
}

// ---------------- Kernel C: fused expert, software-pipelined ----------------
// 256 threads = 4 waves, 1 row per block. Loads for sub n+1 / pair p+1 issued
// in source before the current compute + barriers so L2/HBM latency hides
// under depthwise VALU + MFMA. Pair loop fully unrolled (static reg indexing).
__global__ __launch_bounds__(256, 3) void moe_main(
    const float* __restrict__ x, const float* __restrict__ dw_w,
    const float* __restrict__ dw_b, const float* __restrict__ pw_w,
    const float* __restrict__ pw_b, const float* __restrict__ gate,
    const int* __restrict__ sel, float* __restrict__ out) {
    __shared__ __align__(16) unsigned char hsb[2][WW * KP * 2];  // 12 KB [sub]
    __shared__ unsigned short pwT[2][DIM][KP];                   // 9 KB
    __shared__ float dwc[DIM][12];                               // 4.6 KB

    const int t = threadIdx.x;
    const int r = blockIdx.x;      // 0..127
    const int b = blockIdx.y;      // 0..15
    const int e = sel[b];
    const float g = gate[b];

    const int lane = t & 63, w = t >> 6;
    const int wm = w & 1, wn = w >> 1;
    const int ln = lane & 15, kg = lane >> 4;
    const int cobase = wm * 48, pxbase = wn * 64;

    const int g32 = t & 31;        // px group (4 px each)
    const int p4 = g32 * 4;
    const int cg = t >> 5;         // 0..7 channel group (2 ch each)
    const unsigned swz = (unsigned)((g32 & 7) << 4);
    const float lmask = (p4 == 0) ? 0.f : 1.f;
    const float rmask = (p4 == 124) ? 0.f : 1.f;

    const float m0 = (r > 0) ? 1.f : 0.f;
    const float m2 = (r < HH - 1) ? 1.f : 0.f;
    const int rr0 = (r > 0) ? r - 1 : 0;
    const int rr2 = (r < HH - 1) ? r + 1 : HH - 1;

    // pipeline prologue: issue loads for (pair0, sub0) before dwc staging
    float4 fA[2][3], fB[2][3];
    issue_sub(x, b, 0, cg, rr0, r, rr2, p4, fA);

    // stage depthwise taps + bias, row-edge masks folded in
    for (int j = t; j < DIM * 12; j += 256) {
        const int c = j / 12, q = j - c * 12;
        float v = 0.f;
        if (q < 9) {
            v = dw_w[((size_t)e * DIM + c) * 9 + q];
            if (q < 3) v *= m0;
            if (q >= 6) v *= m2;
        } else if (q == 9) v = dw_b[e * DIM + c];
        dwc[c][q] = v;
    }
    __syncthreads();

    floatx4 acc[3][4];
#pragma unroll
    for (int i = 0; i < 3; ++i)
#pragma unroll
        for (int j = 0; j < 4; ++j) acc[i][j] = (floatx4){0.f, 0.f, 0.f, 0.f};

#pragma unroll
    for (int pair = 0; pair < 3; ++pair) {
        const int cb = pair * 32;
        // issue pw^T loads early (consumed as LDS writes ~250 inst later)
        float2 pwv[2][3];
#pragma unroll
        for (int p = 0; p < 2; ++p)
#pragma unroll
            for (int i2 = 0; i2 < 3; ++i2) {
                const int u2 = i2 * 256 + t;     // 0..767
                const int co = u2 >> 3, kk = (u2 & 7) * 2;
                pwv[p][i2] = *(const float2*)(pw_w +
                    ((size_t)e * DIM + co) * DIM + cb + p * 16 + kk);
            }
        // issue sub1 loads, then compute sub0 from already-in-flight fA
        issue_sub(x, b, cb + 16, cg, rr0, r, rr2, p4, fB);
        compute_sub(fA, dwc, cb, cg, lmask, rmask, hsb[0], p4, swz);
        // issue next pair's sub0 before the barrier+MFMA shadow
        if (pair < 2) issue_sub(x, b, cb + 32, cg, rr0, r, rr2, p4, fA);
        // pw^T LDS writes from registers
#pragma unroll
        for (int p = 0; p < 2; ++p)
#pragma unroll
            for (int i2 = 0; i2 < 3; ++i2) {
                const int u2 = i2 * 256 + t;
                const int co = u2 >> 3, kk = (u2 & 7) * 2;
                *(unsigned*)&pwT[p][co][kk] = pack2(pwv[p][i2].x, pwv[p][i2].y);
            }
        compute_sub(fB, dwc, cb + 16, cg, lmask, rmask, hsb[1], p4, swz);
        __syncthreads();

        // MFMA: K=32 over the two sub-buffers
        const int bufi = kg >> 1, klo = (kg & 1) * 8;
        bf16x8 af[3], bfr[4];
#pragma unroll
        for (int mf = 0; mf < 3; ++mf)
            af[mf] = *(const bf16x8*)&pwT[bufi][cobase + mf * 16 + ln][klo];
#pragma unroll
        for (int nf = 0; nf < 4; ++nf) {
            const int pxv = pxbase + nf * 16 + ln;
            const unsigned boff = (unsigned)((pxv * (KP * 2) + (kg & 1) * 16) ^
                                             (((pxv >> 2) & 7) << 4));
            bfr[nf] = *(const bf16x8*)(hsb[bufi] + boff);
        }
#pragma unroll
        for (int mf = 0; mf < 3; ++mf)
#pragma unroll
            for (int nf = 0; nf < 4; ++nf)
                acc[mf][nf] = __builtin_amdgcn_mfma_f32_16x16x32_bf16(
                    af[mf], bfr[nf], acc[mf][nf], 0, 0, 0);
        __syncthreads();
    }

    // epilogue: bias + gate, coalesced 64B segments
#pragma unroll
    for (int mf = 0; mf < 3; ++mf) {
#pragma unroll
        for (int rr = 0; rr < 4; ++rr) {
            const int co = cobase + mf * 16 + kg * 4 + rr;
            const float bias = pw_b[e * DIM + co];
            float* orow = out + ((size_t)(b * DIM + co) * HH + r) * WW;
#pragma unroll
            for (int nf = 0; nf < 4; ++nf)
                orow[pxbase + nf * 16 + ln] = (acc[mf][nf][rr] + bias) * g;
        }
    }
}

extern "C" void kernel_launch(void* const* d_in, const int* in_sizes, int n_in,
                              void* d_out, int out_size, void* d_ws, size_t ws_size,
                              hipStream_t stream) {
    const float* x    = (const float*)d_in[0];
    const float* dw_w = (const float*)d_in[1];
    const float* dw_b = (const float*)d_in[2];
    const float* pw_w = (const float*)d_in[3];
    const float* pw_b = (const float*)d_in[4];
    const float* rw   = (const float*)d_in[5];
    const float* rb   = (const float*)d_in[6];
    float* out = (float*)d_out;

    float* pooled = (float*)d_ws;              // B*C floats
    float* gate = pooled + BB * DIM;           // B floats
    int* sel = (int*)(gate + BB);              // B ints

    pool_kernel<<<BB * DIM, 256, 0, stream>>>(x, pooled);
    router_kernel<<<1, 64, 0, stream>>>(pooled, rw, rb, gate, sel);
    dim3 grid(HH, BB);
    moe_main<<<grid, 256, 0, stream>>>(x, dw_w, dw_b, pw_w, pw_b, gate, sel, out);
}